// Round 2
// baseline (1387.713 us; speedup 1.0000x reference)
//
#include <hip/hip_runtime.h>

#define NN 16384   // n_nodes
#define DD 64      // feature dim

typedef _Float16 f16x8 __attribute__((ext_vector_type(8)));
typedef short    s16x8 __attribute__((ext_vector_type(8)));
typedef float    f32x4 __attribute__((ext_vector_type(4)));
typedef int      i32x4 __attribute__((ext_vector_type(4)));

// ---------------------------------------------------------------------------
// Pre-pass: convert x (fp32 [NN][64]) into f16, laid out in exact MFMA
// B-fragment order for mfma_f32_16x16x32_f16:
//   ws[((t*4 + c)*64 + l)*8 + j] = x[32*t + (l>>4)*8 + j][c*16 + (l&15)]
// so the GEMM's B-frag load is one contiguous 16B read per (k-tile t, col-tile c).
// Total ws use: 16384*64 f16 = 2 MiB.
// ---------------------------------------------------------------------------
__global__ __launch_bounds__(256) void prep_x(const float* __restrict__ x,
                                              _Float16* __restrict__ ws) {
    int tid = blockIdx.x * 256 + threadIdx.x;   // (t*4+c)*64 + l ; 131072 total
    int l  = tid & 63;
    int tc = tid >> 6;
    int c  = tc & 3;
    int t  = tc >> 2;
    int q  = l >> 4;
    int m  = l & 15;
    int row0 = t * 32 + q * 8;
    int col  = c * 16 + m;
    f16x8 v;
#pragma unroll
    for (int j = 0; j < 8; ++j)
        v[j] = (_Float16)x[(size_t)(row0 + j) * DD + col];
    *(f16x8*)(ws + (size_t)tid * 8) = v;
}

// ---------------------------------------------------------------------------
// Main GEMM: out[64 rows per block] = adj_tile @ x + x.
// 4 waves/block, wave w owns rows [blk*64 + w*16, +16) x all 64 cols.
// K-chunk = 128 (4 k-steps of 32). adj goes global->VGPR directly
// (nontemporal, 2x dwordx4 per k-step per lane); x-frags come from LDS,
// double-buffered, staged from the pre-swizzled ws (L2-hot).
// ---------------------------------------------------------------------------
__global__ __launch_bounds__(256) void graphpool_gemm(const int* __restrict__ adj,
                                                      const float* __restrict__ x,
                                                      const _Float16* __restrict__ xs,
                                                      float* __restrict__ out) {
    __shared__ _Float16 sB[2][8192];   // 2 x 16 KiB

    const int tid = threadIdx.x;
    const int w   = tid >> 6;
    const int l   = tid & 63;
    const int q   = l >> 4;
    const int m   = l & 15;
    const int row16 = blockIdx.x * 64 + w * 16;

    // A: lane l reads adj[row16 + m][k + q*8 .. +8)
    const int* aptr = adj + (size_t)(row16 + m) * NN + q * 8;

    f32x4 acc[4];
#pragma unroll
    for (int c = 0; c < 4; ++c) acc[c] = (f32x4){0.f, 0.f, 0.f, 0.f};

    i32x4 areg[2][4][2];   // [buf][kstep][2x dwordx4] = 8 adj ints per kstep
    f16x8 sreg[4];         // staging regs for next B slab

    auto loadA = [&](int n, int buf) {
#pragma unroll
        for (int s = 0; s < 4; ++s) {
            const i32x4* p = (const i32x4*)(aptr + (size_t)n * 128 + s * 32);
            areg[buf][s][0] = __builtin_nontemporal_load(p);
            areg[buf][s][1] = __builtin_nontemporal_load(p + 1);
        }
    };
    auto stageRead = [&](int n) {
        const f16x8* src = (const f16x8*)(xs + (size_t)n * 8192);
#pragma unroll
        for (int p = 0; p < 4; ++p) sreg[p] = src[p * 256 + tid];
    };
    auto stageWrite = [&](int buf) {
        f16x8* dst = (f16x8*)sB[buf];
#pragma unroll
        for (int p = 0; p < 4; ++p) dst[p * 256 + tid] = sreg[p];
    };

    // prologue: chunk 0 into buf 0
    stageRead(0);
    loadA(0, 0);
    stageWrite(0);
    __syncthreads();

    auto step = [&](int n, int buf, int nb) {
        const bool pf = (n + 1 < NN / 128);
        if (pf) { stageRead(n + 1); loadA(n + 1, nb); }
#pragma unroll
        for (int s = 0; s < 4; ++s) {
            int av[8];
            {
                i32x4 v0 = areg[buf][s][0], v1 = areg[buf][s][1];
                av[0] = v0.x; av[1] = v0.y; av[2] = v0.z; av[3] = v0.w;
                av[4] = v1.x; av[5] = v1.y; av[6] = v1.z; av[7] = v1.w;
            }
            s16x8 ai;
#pragma unroll
            for (int j = 0; j < 8; ++j)
                ai[j] = av[j] ? (short)0x3C00 : (short)0;   // 0/1 -> f16 0.0/1.0
            f16x8 af = __builtin_bit_cast(f16x8, ai);
#pragma unroll
            for (int c = 0; c < 4; ++c) {
                f16x8 bf = *(const f16x8*)&sB[buf][((s * 4 + c) * 64 + l) * 8];
                acc[c] = __builtin_amdgcn_mfma_f32_16x16x32_f16(af, bf, acc[c], 0, 0, 0);
            }
        }
        if (pf) stageWrite(nb);
        __syncthreads();
    };

    for (int n = 0; n < NN / 128; n += 2) {
        step(n,     0, 1);
        step(n + 1, 1, 0);
    }

    // epilogue: C layout col=l&15, row=(l>>4)*4+r ; add self term +x
#pragma unroll
    for (int c = 0; c < 4; ++c) {
#pragma unroll
        for (int r = 0; r < 4; ++r) {
            int row = row16 + q * 4 + r;
            int col = c * 16 + m;
            size_t off = (size_t)row * DD + col;
            out[off] = acc[c][r] + x[off];
        }
    }
}

// ---------------------------------------------------------------------------
// Safety-net fallback if ws is too small for the swizzled x (2 MiB).
// ---------------------------------------------------------------------------
__global__ void graphpool_fallback(const int* __restrict__ adj,
                                   const float* __restrict__ x,
                                   float* __restrict__ out) {
    int i = blockIdx.x;
    int d = threadIdx.x;   // 64 threads
    float acc = x[(size_t)i * DD + d];
    const int* row = adj + (size_t)i * NN;
    for (int j = 0; j < NN; ++j)
        if (row[j]) acc += x[(size_t)j * DD + d];
    out[(size_t)i * DD + d] = acc;
}

extern "C" void kernel_launch(void* const* d_in, const int* in_sizes, int n_in,
                              void* d_out, int out_size, void* d_ws, size_t ws_size,
                              hipStream_t stream) {
    const float* x   = (const float*)d_in[0];
    const int*   adj = (const int*)d_in[1];
    float*       out = (float*)d_out;

    const size_t ws_needed = (size_t)NN * DD * sizeof(_Float16);   // 2 MiB
    if (ws_size >= ws_needed) {
        _Float16* xs = (_Float16*)d_ws;
        prep_x<<<512, 256, 0, stream>>>(x, xs);
        graphpool_gemm<<<NN / 64, 256, 0, stream>>>(adj, x, xs, out);
    } else {
        graphpool_fallback<<<NN, 64, 0, stream>>>(adj, x, out);
    }
}